// Round 2
// baseline (1098.076 us; speedup 1.0000x reference)
//
#include <hip/hip_runtime.h>
#include <hip/hip_bf16.h>
#include <stdint.h>

// Problem constants
#define BB 2
#define LL 1024
#define DMODEL 2048
#define DINNER 4096
#define DSTATE 16
#define DTRANK 128
#define XDBL_LD 256   // x_proj rows padded 160 -> 256

typedef unsigned short ushort;
using short8 = __attribute__((ext_vector_type(8))) short;
using f32x4  = __attribute__((ext_vector_type(4))) float;
using us4    = __attribute__((ext_vector_type(4))) ushort;

__device__ __forceinline__ float bf2f(ushort u) {
    union { uint32_t i; float f; } v; v.i = ((uint32_t)u) << 16; return v.f;
}
__device__ __forceinline__ ushort f2bf(float f) {
    union { float f; uint32_t i; } v; v.f = f;
    uint32_t lsb = (v.i >> 16) & 1u;
    uint32_t r = v.i + 0x7FFFu + lsb;   // RNE
    return (ushort)(r >> 16);
}

// ---------------------------------------------------------------------------
// f32 -> bf16 bulk convert (n divisible by 1024)
// ---------------------------------------------------------------------------
__global__ __launch_bounds__(256) void cvt_kernel(
    const float4* __restrict__ in, us4* __restrict__ out, int n4)
{
    int i = blockIdx.x * 256 + threadIdx.x;
    if (i < n4) {
        float4 v = in[i];
        us4 o;
        o.x = f2bf(v.x); o.y = f2bf(v.y); o.z = f2bf(v.z); o.w = f2bf(v.w);
        out[i] = o;
    }
}

// Zero-pad + convert x_proj_w (160 x 4096 f32) -> (256 x 4096 bf16)
__global__ __launch_bounds__(256) void pad_xproj(
    const float* __restrict__ w, ushort* __restrict__ wp)
{
    int gid = blockIdx.x * 256 + threadIdx.x;   // over 256*4096
    int r = gid >> 12;
    wp[gid] = (r < 160) ? f2bf(w[gid]) : (ushort)0;
}

// ---------------------------------------------------------------------------
// Generic NT GEMM: C[M,N] = A[M,K] (bf16, row-major, lda) * B[N,K]^T (bf16,
// row-major, ldb). 128x128 block tile, 4 waves of 64x64, 16x16x32 bf16 MFMA.
// M,N multiples of 128; K multiple of 32.
// EPI: 0 = none, 1 = per-col f32 bias + softplus.
// WF/WH: write fp32 / bf16 outputs.
// ---------------------------------------------------------------------------
template <int EPI, bool WF, bool WH>
__global__ __launch_bounds__(256) void gemm_nt(
    const ushort* __restrict__ A, int lda,
    const ushort* __restrict__ Bm, int ldb,
    float* __restrict__ Cf, ushort* __restrict__ Ch, int ldc,
    int K, const float* __restrict__ bias)
{
    __shared__ __align__(16) ushort sA[128 * 32];
    __shared__ __align__(16) ushort sB[128 * 32];

    const int tid  = threadIdx.x;
    const int lane = tid & 63;
    const int wave = tid >> 6;
    const int wr = wave >> 1, wc = wave & 1;
    const long m0 = (long)blockIdx.y * 128;
    const long n0 = (long)blockIdx.x * 128;

    f32x4 acc[4][4] = {};

    const int lrow = lane & 15;          // fragment row/col within 16-tile
    const int lko  = (lane >> 4) << 3;   // k-offset (elements) within 32

    for (int k0 = 0; k0 < K; k0 += 32) {
        #pragma unroll
        for (int half = 0; half < 2; ++half) {
            int c   = half * 256 + tid;
            int row = c >> 2;
            int col = (c & 3) << 3;
            short8 va = *(const short8*)(A  + (m0 + row) * (long)lda + k0 + col);
            short8 vb = *(const short8*)(Bm + (n0 + row) * (long)ldb + k0 + col);
            *(short8*)&sA[c * 8] = va;
            *(short8*)&sB[c * 8] = vb;
        }
        __syncthreads();

        short8 af[4], bf[4];
        #pragma unroll
        for (int i = 0; i < 4; ++i)
            af[i] = *(const short8*)&sA[(wr * 64 + i * 16 + lrow) * 32 + lko];
        #pragma unroll
        for (int j = 0; j < 4; ++j)
            bf[j] = *(const short8*)&sB[(wc * 64 + j * 16 + lrow) * 32 + lko];

        #pragma unroll
        for (int i = 0; i < 4; ++i)
            #pragma unroll
            for (int j = 0; j < 4; ++j)
                acc[i][j] = __builtin_amdgcn_mfma_f32_16x16x32_bf16(
                    af[i], bf[j], acc[i][j], 0, 0, 0);
        __syncthreads();
    }

    // Epilogue. C/D mapping (verified m89/m91): col = lane&15, row = (lane>>4)*4 + reg.
    const int r0 = (lane >> 4) * 4;
    const int c0 = lane & 15;
    #pragma unroll
    for (int i = 0; i < 4; ++i) {
        #pragma unroll
        for (int j = 0; j < 4; ++j) {
            long col = n0 + wc * 64 + j * 16 + c0;
            float bv = 0.f;
            if (EPI == 1) bv = bias[col];
            #pragma unroll
            for (int r = 0; r < 4; ++r) {
                long row = m0 + wr * 64 + i * 16 + r0 + r;
                float v = acc[i][j][r];
                if (EPI == 1) {
                    v += bv;
                    v = (v > 20.f) ? v : log1pf(__expf(v));  // softplus
                }
                long idx = row * (long)ldc + col;
                if (WF) Cf[idx] = v;
                if (WH) Ch[idx] = f2bf(v);
            }
        }
    }
}

// ---------------------------------------------------------------------------
// Depthwise causal conv(4) + bias + SiLU. xz layout (bf16): row (b*L+l), 8192
// cols (x: 0..4095, z: 4096..8191). Writes bf16 x_conv (row, 4096).
// ---------------------------------------------------------------------------
__global__ __launch_bounds__(256) void conv_silu_kernel(
    const ushort* __restrict__ xz,
    const float* __restrict__ cw,
    const float* __restrict__ cb,
    ushort* __restrict__ xc)
{
    int gid = blockIdx.x * 256 + threadIdx.x;   // over 2048*4096
    int d  = gid & (DINNER - 1);
    int rl = gid >> 12;                         // b*L + l
    int l  = rl & (LL - 1);
    float acc = cb[d];
    #pragma unroll
    for (int j = 0; j < 4; ++j) {
        int li = l - 3 + j;
        if (li >= 0)
            acc += cw[d * 4 + j] * bf2f(xz[(long)(rl - 3 + j) * 8192 + d]);
    }
    float s = acc / (1.f + __expf(-acc));       // SiLU
    xc[gid] = f2bf(s);
}

// ---------------------------------------------------------------------------
// Selective scan: one thread per (b,d) channel, sequential over L.
// Fused: y = (scan + x*D) * silu(z), written as bf16 for out_proj GEMM.
// ---------------------------------------------------------------------------
__global__ __launch_bounds__(256) void scan_kernel(
    const ushort* __restrict__ delta,  // (2048, 4096) bf16
    const ushort* __restrict__ xc,     // (2048, 4096) bf16
    const float* __restrict__ xdbl,    // (2048, 256) f32; B at col 128+, C at 144+
    const ushort* __restrict__ xz,     // (2048, 8192) bf16; z at col 4096+d
    const float* __restrict__ A_log,   // (4096, 16) f32
    const float* __restrict__ Dp,      // (4096,) f32
    ushort* __restrict__ y)            // (2048, 4096) bf16
{
    const int b = blockIdx.x >> 4;
    const int d = (blockIdx.x & 15) * 256 + threadIdx.x;

    float Arow[DSTATE];
    #pragma unroll
    for (int s = 0; s < DSTATE; ++s)
        Arow[s] = -__expf(A_log[d * DSTATE + s]);
    const float Dd = Dp[d];

    float h[DSTATE];
    #pragma unroll
    for (int s = 0; s < DSTATE; ++s) h[s] = 0.f;

    const long base = (long)b * LL;
    for (int t = 0; t < LL; ++t) {
        const long row = base + t;
        const float dt = bf2f(delta[row * DINNER + d]);
        const float xv = bf2f(xc[row * DINNER + d]);
        const float dx = dt * xv;
        const float* bc = xdbl + row * XDBL_LD + DTRANK;  // B then C, uniform
        float yt = 0.f;
        #pragma unroll
        for (int s = 0; s < DSTATE; ++s) {
            float dA = __expf(dt * Arow[s]);
            h[s] = h[s] * dA + dx * bc[s];
            yt += h[s] * bc[DSTATE + s];
        }
        yt += xv * Dd;
        const float zv = bf2f(xz[row * 8192 + DINNER + d]);
        const float sz = zv / (1.f + __expf(-zv));        // silu(z)
        y[row * DINNER + d] = f2bf(yt * sz);
    }
}

// ---------------------------------------------------------------------------
extern "C" void kernel_launch(void* const* d_in, const int* in_sizes, int n_in,
                              void* d_out, int out_size, void* d_ws, size_t ws_size,
                              hipStream_t stream)
{
    const float* hidden    = (const float*)d_in[0];  // (2,1024,2048)
    const float* in_proj   = (const float*)d_in[1];  // (8192,2048)
    const float* conv_w    = (const float*)d_in[2];  // (4096,4)
    const float* conv_b    = (const float*)d_in[3];  // (4096,)
    const float* x_proj    = (const float*)d_in[4];  // (160,4096)
    const float* dt_proj_w = (const float*)d_in[5];  // (4096,128)
    const float* dt_proj_b = (const float*)d_in[6];  // (4096,)
    const float* A_log     = (const float*)d_in[7];  // (4096,16)
    const float* Dp        = (const float*)d_in[8];  // (4096,)
    const float* out_proj  = (const float*)d_in[9];  // (2048,4096)
    float* out = (float*)d_out;                      // (2,1024,2048) f32

    // Workspace layout (bytes, all 16B aligned)
    char* ws = (char*)d_ws;
    ushort* xz_h    = (ushort*)(ws);                // 2048*8192 bf16 = 32 MiB
    ushort* xc      = (ushort*)(ws + 33554432);     // 2048*4096 bf16 = 16 MiB
    ushort* xpp     = (ushort*)(ws + 50331648);     // 256*4096 bf16 = 2 MiB
    float*  xdbl    = (float*)(ws + 52428800);      // 2048*256 f32 = 2 MiB
    ushort* xdblh   = (ushort*)(ws + 54525952);     // 2048*256 bf16 = 1 MiB
    ushort* delta_h = (ushort*)(ws + 55574528);     // 2048*4096 bf16 = 16 MiB
    ushort* yb      = (ushort*)(ws + 72351744);     // 2048*4096 bf16 = 16 MiB
    ushort* hid_h   = (ushort*)(ws + 89128960);     // 2048*2048 bf16 = 8 MiB
    ushort* inp_h   = (ushort*)(ws + 97517568);     // 8192*2048 bf16 = 32 MiB
    ushort* dtp_h   = (ushort*)(ws + 131072000);    // 4096*128 bf16 = 1 MiB
    ushort* outp_h  = (ushort*)(ws + 132120576);    // 2048*4096 bf16 = 16 MiB

    const int M = BB * LL;  // 2048

    // 0) f32 -> bf16 weight/activation conversions
    cvt_kernel<<<(2048 * 2048) / 1024, 256, 0, stream>>>(
        (const float4*)hidden, (us4*)hid_h, (2048 * 2048) / 4);
    cvt_kernel<<<(8192 * 2048) / 1024, 256, 0, stream>>>(
        (const float4*)in_proj, (us4*)inp_h, (8192 * 2048) / 4);
    cvt_kernel<<<(4096 * 128) / 1024, 256, 0, stream>>>(
        (const float4*)dt_proj_w, (us4*)dtp_h, (4096 * 128) / 4);
    cvt_kernel<<<(2048 * 4096) / 1024, 256, 0, stream>>>(
        (const float4*)out_proj, (us4*)outp_h, (2048 * 4096) / 4);
    pad_xproj<<<(256 * 4096) / 256, 256, 0, stream>>>(x_proj, xpp);

    // 1) xz = hidden @ in_proj^T   (2048x8192 bf16)
    gemm_nt<0, false, true><<<dim3(8192 / 128, M / 128), 256, 0, stream>>>(
        hid_h, DMODEL, inp_h, DMODEL, nullptr, xz_h, 8192, DMODEL, nullptr);

    // 2) x_conv = silu(causal_conv(x) + conv_b)  (bf16)
    conv_silu_kernel<<<(M * DINNER) / 256, 256, 0, stream>>>(xz_h, conv_w, conv_b, xc);

    // 3) x_dbl = x_conv @ x_proj_pad^T  (2048x256, f32 + bf16)
    gemm_nt<0, true, true><<<dim3(XDBL_LD / 128, M / 128), 256, 0, stream>>>(
        xc, DINNER, xpp, DINNER, xdbl, xdblh, XDBL_LD, DINNER, nullptr);

    // 4) delta = softplus(dt_lo @ dt_proj_w^T + dt_proj_b)  (2048x4096 bf16)
    gemm_nt<1, false, true><<<dim3(DINNER / 128, M / 128), 256, 0, stream>>>(
        xdblh, XDBL_LD, dtp_h, DTRANK, nullptr, delta_h, DINNER, DTRANK, dt_proj_b);

    // 5) selective scan + D-skip + silu(z) gating -> y (bf16)
    scan_kernel<<<BB * (DINNER / 256), 256, 0, stream>>>(
        delta_h, xc, xdbl, xz_h, A_log, Dp, yb);

    // 6) out = y @ out_proj^T  (2048x2048 f32)
    gemm_nt<0, true, false><<<dim3(DMODEL / 128, M / 128), 256, 0, stream>>>(
        yb, DINNER, outp_h, DINNER, out, nullptr, DMODEL, DINNER, nullptr);
}

// Round 3
// 650.690 us; speedup vs baseline: 1.6876x; 1.6876x over previous
//
#include <hip/hip_runtime.h>
#include <hip/hip_bf16.h>
#include <stdint.h>

// Problem constants
#define BB 2
#define LL 1024
#define DMODEL 2048
#define DINNER 4096
#define DSTATE 16
#define DTRANK 128
#define XDBL_LD 256   // x_proj rows padded 160 -> 256
#define CHUNK 64
#define NCH (LL / CHUNK)   // 16

typedef unsigned short ushort;
using short8 = __attribute__((ext_vector_type(8))) short;
using f32x4  = __attribute__((ext_vector_type(4))) float;
using us4    = __attribute__((ext_vector_type(4))) ushort;

__device__ __forceinline__ float bf2f(ushort u) {
    union { uint32_t i; float f; } v; v.i = ((uint32_t)u) << 16; return v.f;
}
__device__ __forceinline__ ushort f2bf(float f) {
    union { float f; uint32_t i; } v; v.f = f;
    uint32_t lsb = (v.i >> 16) & 1u;
    uint32_t r = v.i + 0x7FFFu + lsb;   // RNE
    return (ushort)(r >> 16);
}

// ---------------------------------------------------------------------------
// f32 -> bf16 bulk convert
// ---------------------------------------------------------------------------
__global__ __launch_bounds__(256) void cvt_kernel(
    const float4* __restrict__ in, us4* __restrict__ out, int n4)
{
    int i = blockIdx.x * 256 + threadIdx.x;
    if (i < n4) {
        float4 v = in[i];
        us4 o;
        o.x = f2bf(v.x); o.y = f2bf(v.y); o.z = f2bf(v.z); o.w = f2bf(v.w);
        out[i] = o;
    }
}

// Zero-pad + convert x_proj_w (160 x 4096 f32) -> (256 x 4096 bf16)
__global__ __launch_bounds__(256) void pad_xproj(
    const float* __restrict__ w, ushort* __restrict__ wp)
{
    int gid = blockIdx.x * 256 + threadIdx.x;   // over 256*4096
    int r = gid >> 12;
    wp[gid] = (r < 160) ? f2bf(w[gid]) : (ushort)0;
}

// ---------------------------------------------------------------------------
// Generic NT GEMM: C[M,N] = A[M,K] bf16 row-major * B[N,K]^T bf16 row-major.
// 128x128 block tile, 4 waves of 64x64, 16x16x32 bf16 MFMA.
// ---------------------------------------------------------------------------
template <int EPI, bool WF, bool WH>
__global__ __launch_bounds__(256) void gemm_nt(
    const ushort* __restrict__ A, int lda,
    const ushort* __restrict__ Bm, int ldb,
    float* __restrict__ Cf, ushort* __restrict__ Ch, int ldc,
    int K, const float* __restrict__ bias)
{
    __shared__ __align__(16) ushort sA[128 * 32];
    __shared__ __align__(16) ushort sB[128 * 32];

    const int tid  = threadIdx.x;
    const int lane = tid & 63;
    const int wave = tid >> 6;
    const int wr = wave >> 1, wc = wave & 1;
    const long m0 = (long)blockIdx.y * 128;
    const long n0 = (long)blockIdx.x * 128;

    f32x4 acc[4][4] = {};

    const int lrow = lane & 15;
    const int lko  = (lane >> 4) << 3;

    for (int k0 = 0; k0 < K; k0 += 32) {
        #pragma unroll
        for (int half = 0; half < 2; ++half) {
            int c   = half * 256 + tid;
            int row = c >> 2;
            int col = (c & 3) << 3;
            short8 va = *(const short8*)(A  + (m0 + row) * (long)lda + k0 + col);
            short8 vb = *(const short8*)(Bm + (n0 + row) * (long)ldb + k0 + col);
            *(short8*)&sA[c * 8] = va;
            *(short8*)&sB[c * 8] = vb;
        }
        __syncthreads();

        short8 af[4], bf[4];
        #pragma unroll
        for (int i = 0; i < 4; ++i)
            af[i] = *(const short8*)&sA[(wr * 64 + i * 16 + lrow) * 32 + lko];
        #pragma unroll
        for (int j = 0; j < 4; ++j)
            bf[j] = *(const short8*)&sB[(wc * 64 + j * 16 + lrow) * 32 + lko];

        #pragma unroll
        for (int i = 0; i < 4; ++i)
            #pragma unroll
            for (int j = 0; j < 4; ++j)
                acc[i][j] = __builtin_amdgcn_mfma_f32_16x16x32_bf16(
                    af[i], bf[j], acc[i][j], 0, 0, 0);
        __syncthreads();
    }

    // C/D mapping: col = lane&15, row = (lane>>4)*4 + reg.
    const int r0 = (lane >> 4) * 4;
    const int c0 = lane & 15;
    #pragma unroll
    for (int i = 0; i < 4; ++i) {
        #pragma unroll
        for (int j = 0; j < 4; ++j) {
            long col = n0 + wc * 64 + j * 16 + c0;
            float bv = 0.f;
            if (EPI == 1) bv = bias[col];
            #pragma unroll
            for (int r = 0; r < 4; ++r) {
                long row = m0 + wr * 64 + i * 16 + r0 + r;
                float v = acc[i][j][r];
                if (EPI == 1) {
                    v += bv;
                    v = (v > 20.f) ? v : log1pf(__expf(v));  // softplus
                }
                long idx = row * (long)ldc + col;
                if (WF) Cf[idx] = v;
                if (WH) Ch[idx] = f2bf(v);
            }
        }
    }
}

// ---------------------------------------------------------------------------
// Depthwise causal conv(4) + bias + SiLU.
// ---------------------------------------------------------------------------
__global__ __launch_bounds__(256) void conv_silu_kernel(
    const ushort* __restrict__ xz,
    const float* __restrict__ cw,
    const float* __restrict__ cb,
    ushort* __restrict__ xc)
{
    int gid = blockIdx.x * 256 + threadIdx.x;   // over 2048*4096
    int d  = gid & (DINNER - 1);
    int rl = gid >> 12;
    int l  = rl & (LL - 1);
    float acc = cb[d];
    #pragma unroll
    for (int j = 0; j < 4; ++j) {
        int li = l - 3 + j;
        if (li >= 0)
            acc += cw[d * 4 + j] * bf2f(xz[(long)(rl - 3 + j) * 8192 + d]);
    }
    float s = acc / (1.f + __expf(-acc));
    xc[gid] = f2bf(s);
}

// ---------------------------------------------------------------------------
// Chunked selective scan.
// P1: per (b,chunk,d) local scan from h=0 -> H[16] end-state + sum(dt).
// P2: per (b,d,s) prefix over 16 chunks; rewrites Hbuf with INCOMING state.
// P3: per (b,chunk,d) rerun chunk from incoming state, fused D-skip +
//     silu(z) gating -> y (bf16).
// ---------------------------------------------------------------------------
__global__ __launch_bounds__(256) void scan_p1(
    const ushort* __restrict__ delta,  // (2048,4096) bf16
    const ushort* __restrict__ xc,     // (2048,4096) bf16
    const float*  __restrict__ xdbl,   // (2048,256) f32; B at col 128
    const float*  __restrict__ A_log,  // (4096,16) f32
    float* __restrict__ Hbuf,          // (2,16,4096,16) f32
    float* __restrict__ sumdt_buf)     // (2,16,4096) f32
{
    __shared__ float sB[CHUNK * 16];
    const int tid = threadIdx.x;
    const int k = blockIdx.y, b = blockIdx.z;
    const int d = blockIdx.x * 256 + tid;
    const int row0 = b * LL + k * CHUNK;

    #pragma unroll
    for (int i = 0; i < 4; ++i) {
        int idx = i * 256 + tid;                 // = t*16 + s
        sB[idx] = xdbl[(long)(row0 + (idx >> 4)) * XDBL_LD + DTRANK + (idx & 15)];
    }
    __syncthreads();

    float A[DSTATE];
    const float4* Ap = (const float4*)(A_log + d * DSTATE);
    #pragma unroll
    for (int i = 0; i < 4; ++i) {
        float4 v = Ap[i];
        A[i*4+0] = -__expf(v.x); A[i*4+1] = -__expf(v.y);
        A[i*4+2] = -__expf(v.z); A[i*4+3] = -__expf(v.w);
    }

    float H[DSTATE];
    #pragma unroll
    for (int s = 0; s < DSTATE; ++s) H[s] = 0.f;
    float sumdt = 0.f;

    for (int t = 0; t < CHUNK; ++t) {
        const long row = row0 + t;
        const float dt = bf2f(delta[row * DINNER + d]);
        const float xv = bf2f(xc[row * DINNER + d]);
        const float dx = dt * xv;
        sumdt += dt;
        #pragma unroll
        for (int s = 0; s < DSTATE; ++s) {
            float dA = __expf(dt * A[s]);
            H[s] = H[s] * dA + dx * sB[t * 16 + s];
        }
    }

    const long o = ((long)(b * NCH + k) * DINNER + d) * DSTATE;
    float4* Ho = (float4*)(Hbuf + o);
    #pragma unroll
    for (int i = 0; i < 4; ++i) {
        float4 v; v.x = H[i*4+0]; v.y = H[i*4+1]; v.z = H[i*4+2]; v.w = H[i*4+3];
        Ho[i] = v;
    }
    sumdt_buf[(b * NCH + k) * DINNER + d] = sumdt;
}

__global__ __launch_bounds__(256) void scan_p2(
    const float* __restrict__ A_log,
    const float* __restrict__ sumdt_buf,
    float* __restrict__ Hbuf)          // in: local H; out: incoming state
{
    int gid = blockIdx.x * 256 + threadIdx.x;   // 131072 = 2*4096*16
    int b = gid >> 16;
    int rem = gid & 65535;
    int d = rem >> 4, s = rem & 15;
    float A = -__expf(A_log[d * DSTATE + s]);
    float h = 0.f;
    for (int k = 0; k < NCH; ++k) {
        long idx = ((long)(b * NCH + k) * DINNER + d) * DSTATE + s;
        float Hk = Hbuf[idx];
        float sd = sumdt_buf[(b * NCH + k) * DINNER + d];
        Hbuf[idx] = h;
        h = h * __expf(A * sd) + Hk;
    }
}

__global__ __launch_bounds__(256) void scan_p3(
    const ushort* __restrict__ delta,
    const ushort* __restrict__ xc,
    const float*  __restrict__ xdbl,
    const ushort* __restrict__ xz,     // (2048,8192) bf16; z at col 4096+d
    const float*  __restrict__ A_log,
    const float*  __restrict__ Dp,
    const float*  __restrict__ hin,    // (2,16,4096,16) incoming states
    ushort* __restrict__ y)            // (2048,4096) bf16
{
    __shared__ float sBC[CHUNK * 32];
    const int tid = threadIdx.x;
    const int k = blockIdx.y, b = blockIdx.z;
    const int d = blockIdx.x * 256 + tid;
    const int row0 = b * LL + k * CHUNK;

    #pragma unroll
    for (int i = 0; i < 8; ++i) {
        int idx = i * 256 + tid;                 // = t*32 + c
        sBC[idx] = xdbl[(long)(row0 + (idx >> 5)) * XDBL_LD + DTRANK + (idx & 31)];
    }
    __syncthreads();

    float A[DSTATE];
    const float4* Ap = (const float4*)(A_log + d * DSTATE);
    #pragma unroll
    for (int i = 0; i < 4; ++i) {
        float4 v = Ap[i];
        A[i*4+0] = -__expf(v.x); A[i*4+1] = -__expf(v.y);
        A[i*4+2] = -__expf(v.z); A[i*4+3] = -__expf(v.w);
    }
    const float Dd = Dp[d];

    float h[DSTATE];
    const float4* Hp = (const float4*)(hin + ((long)(b * NCH + k) * DINNER + d) * DSTATE);
    #pragma unroll
    for (int i = 0; i < 4; ++i) {
        float4 v = Hp[i];
        h[i*4+0] = v.x; h[i*4+1] = v.y; h[i*4+2] = v.z; h[i*4+3] = v.w;
    }

    for (int t = 0; t < CHUNK; ++t) {
        const long row = row0 + t;
        const float dt = bf2f(delta[row * DINNER + d]);
        const float xv = bf2f(xc[row * DINNER + d]);
        const float dx = dt * xv;
        float yt = 0.f;
        #pragma unroll
        for (int s = 0; s < DSTATE; ++s) {
            float dA = __expf(dt * A[s]);
            h[s] = h[s] * dA + dx * sBC[t * 32 + s];
            yt += h[s] * sBC[t * 32 + 16 + s];
        }
        yt += xv * Dd;
        const float zv = bf2f(xz[row * 8192 + DINNER + d]);
        yt *= zv / (1.f + __expf(-zv));
        y[row * DINNER + d] = f2bf(yt);
    }
}

// ---------------------------------------------------------------------------
extern "C" void kernel_launch(void* const* d_in, const int* in_sizes, int n_in,
                              void* d_out, int out_size, void* d_ws, size_t ws_size,
                              hipStream_t stream)
{
    const float* hidden    = (const float*)d_in[0];
    const float* in_proj   = (const float*)d_in[1];
    const float* conv_w    = (const float*)d_in[2];
    const float* conv_b    = (const float*)d_in[3];
    const float* x_proj    = (const float*)d_in[4];
    const float* dt_proj_w = (const float*)d_in[5];
    const float* dt_proj_b = (const float*)d_in[6];
    const float* A_log     = (const float*)d_in[7];
    const float* Dp        = (const float*)d_in[8];
    const float* out_proj  = (const float*)d_in[9];
    float* out = (float*)d_out;

    // Workspace layout (bytes, all 16B aligned)
    char* ws = (char*)d_ws;
    ushort* xz_h    = (ushort*)(ws);                // 32 MiB
    ushort* xc      = (ushort*)(ws + 33554432);     // 16 MiB
    ushort* xpp     = (ushort*)(ws + 50331648);     // 2 MiB
    float*  xdbl    = (float*)(ws + 52428800);      // 2 MiB
    ushort* xdblh   = (ushort*)(ws + 54525952);     // 1 MiB
    ushort* delta_h = (ushort*)(ws + 55574528);     // 16 MiB
    ushort* yb      = (ushort*)(ws + 72351744);     // 16 MiB
    ushort* hid_h   = (ushort*)(ws + 89128960);     // 8 MiB
    ushort* inp_h   = (ushort*)(ws + 97517568);     // 32 MiB (dead after gemm1)
    ushort* dtp_h   = (ushort*)(ws + 131072000);    // 1 MiB
    ushort* outp_h  = (ushort*)(ws + 132120576);    // 16 MiB
    // Scan scratch aliases inp_h's region (dead by scan time):
    float*  Hbuf    = (float*)(ws + 97517568);      // 2*16*4096*16 f32 = 8 MiB
    float*  sumdt   = (float*)(ws + 105906176);     // 2*16*4096 f32 = 512 KiB

    const int M = BB * LL;  // 2048

    // 0) f32 -> bf16 conversions
    cvt_kernel<<<(2048 * 2048) / 1024, 256, 0, stream>>>(
        (const float4*)hidden, (us4*)hid_h, (2048 * 2048) / 4);
    cvt_kernel<<<(8192 * 2048) / 1024, 256, 0, stream>>>(
        (const float4*)in_proj, (us4*)inp_h, (8192 * 2048) / 4);
    cvt_kernel<<<(4096 * 128) / 1024, 256, 0, stream>>>(
        (const float4*)dt_proj_w, (us4*)dtp_h, (4096 * 128) / 4);
    cvt_kernel<<<(2048 * 4096) / 1024, 256, 0, stream>>>(
        (const float4*)out_proj, (us4*)outp_h, (2048 * 4096) / 4);
    pad_xproj<<<(256 * 4096) / 256, 256, 0, stream>>>(x_proj, xpp);

    // 1) xz = hidden @ in_proj^T   (2048x8192 bf16)
    gemm_nt<0, false, true><<<dim3(8192 / 128, M / 128), 256, 0, stream>>>(
        hid_h, DMODEL, inp_h, DMODEL, nullptr, xz_h, 8192, DMODEL, nullptr);

    // 2) x_conv = silu(causal_conv(x) + conv_b)
    conv_silu_kernel<<<(M * DINNER) / 256, 256, 0, stream>>>(xz_h, conv_w, conv_b, xc);

    // 3) x_dbl = x_conv @ x_proj_pad^T  (2048x256, f32 + bf16)
    gemm_nt<0, true, true><<<dim3(XDBL_LD / 128, M / 128), 256, 0, stream>>>(
        xc, DINNER, xpp, DINNER, xdbl, xdblh, XDBL_LD, DINNER, nullptr);

    // 4) delta = softplus(dt_lo @ dt_proj_w^T + dt_proj_b)  (bf16)
    gemm_nt<1, false, true><<<dim3(DINNER / 128, M / 128), 256, 0, stream>>>(
        xdblh, XDBL_LD, dtp_h, DTRANK, nullptr, delta_h, DINNER, DTRANK, dt_proj_b);

    // 5) chunked selective scan + D-skip + silu(z) gating -> y (bf16)
    scan_p1<<<dim3(DINNER / 256, NCH, BB), 256, 0, stream>>>(
        delta_h, xc, xdbl, A_log, Hbuf, sumdt);
    scan_p2<<<(BB * DINNER * DSTATE) / 256, 256, 0, stream>>>(
        A_log, sumdt, Hbuf);
    scan_p3<<<dim3(DINNER / 256, NCH, BB), 256, 0, stream>>>(
        delta_h, xc, xdbl, xz_h, A_log, Dp, Hbuf, yb);

    // 6) out = y @ out_proj^T  (2048x2048 f32)
    gemm_nt<0, true, false><<<dim3(DMODEL / 128, M / 128), 256, 0, stream>>>(
        yb, DINNER, outp_h, DINNER, out, nullptr, DMODEL, DINNER, nullptr);
}

// Round 4
// 517.024 us; speedup vs baseline: 2.1238x; 1.2585x over previous
//
#include <hip/hip_runtime.h>
#include <hip/hip_bf16.h>
#include <stdint.h>

// Problem constants
#define BB 2
#define LL 1024
#define DMODEL 2048
#define DINNER 4096
#define DSTATE 16
#define DTRANK 128
#define XDBL_LD 256   // x_proj rows padded 160 -> 256
#define CHUNK 64
#define NCH (LL / CHUNK)   // 16

typedef unsigned short ushort;
using short8 = __attribute__((ext_vector_type(8))) short;
using f32x4  = __attribute__((ext_vector_type(4))) float;
using us4    = __attribute__((ext_vector_type(4))) ushort;

__device__ __forceinline__ float bf2f(ushort u) {
    union { uint32_t i; float f; } v; v.i = ((uint32_t)u) << 16; return v.f;
}
__device__ __forceinline__ ushort f2bf(float f) {
    union { float f; uint32_t i; } v; v.f = f;
    uint32_t lsb = (v.i >> 16) & 1u;
    uint32_t r = v.i + 0x7FFFu + lsb;   // RNE
    return (ushort)(r >> 16);
}

// Async global->LDS, 16B per lane. LDS dest = wave-uniform base + lane*16,
// so lds ptr must be computed as base + tid*16 (lane-ordered, unpadded).
__device__ __forceinline__ void glds16(const ushort* g, ushort* l) {
    __builtin_amdgcn_global_load_lds(
        (const __attribute__((address_space(1))) void*)g,
        (__attribute__((address_space(3))) void*)l,
        16, 0, 0);
}

// ---------------------------------------------------------------------------
// f32 -> bf16 bulk convert
// ---------------------------------------------------------------------------
__global__ __launch_bounds__(256) void cvt_kernel(
    const float4* __restrict__ in, us4* __restrict__ out, int n4)
{
    int i = blockIdx.x * 256 + threadIdx.x;
    if (i < n4) {
        float4 v = in[i];
        us4 o;
        o.x = f2bf(v.x); o.y = f2bf(v.y); o.z = f2bf(v.z); o.w = f2bf(v.w);
        out[i] = o;
    }
}

// Zero-pad + convert x_proj_w (160 x 4096 f32) -> (256 x 4096 bf16)
__global__ __launch_bounds__(256) void pad_xproj(
    const float* __restrict__ w, ushort* __restrict__ wp)
{
    int gid = blockIdx.x * 256 + threadIdx.x;   // over 256*4096
    int r = gid >> 12;
    wp[gid] = (r < 160) ? f2bf(w[gid]) : (ushort)0;
}

// ---------------------------------------------------------------------------
// Generic NT GEMM: C[M,N] = A[M,K] bf16 row-major * B[N,K]^T bf16 row-major.
// 128x128 tile, 4 waves of 64x64, 16x16x32 bf16 MFMA, global_load_lds
// staging (m97 structure). Optional K-split via blockIdx.z: A/B advance by
// z*K elements in K; Cf/Ch advance by z*Mrows*ldc (per-split partials).
// ---------------------------------------------------------------------------
template <int EPI, bool WF, bool WH>
__global__ __launch_bounds__(256) void gemm_nt(
    const ushort* __restrict__ A, int lda,
    const ushort* __restrict__ Bm, int ldb,
    float* __restrict__ Cf, ushort* __restrict__ Ch, int ldc,
    int K, const float* __restrict__ bias)
{
    __shared__ __align__(16) ushort sA[128 * 32];
    __shared__ __align__(16) ushort sB[128 * 32];

    const int tid  = threadIdx.x;
    const int lane = tid & 63;
    const int wave = tid >> 6;
    const int wr = wave >> 1, wc = wave & 1;
    const long m0 = (long)blockIdx.y * 128;
    const long n0 = (long)blockIdx.x * 128;

    // K-split offsets
    const long zoff = (long)blockIdx.z;
    A  += zoff * (long)K;
    Bm += zoff * (long)K;
    const long Mrows = (long)gridDim.y * 128;
    if (WF) Cf += zoff * Mrows * (long)ldc;
    if (WH) Ch += zoff * Mrows * (long)ldc;

    f32x4 acc[4][4] = {};

    const int lrow = lane & 15;
    const int lko  = (lane >> 4) << 3;

    // staging geometry: thread t covers tile byte offset t*16 (and +4096)
    const int sr = tid >> 2;            // row 0..63 (q=1 adds 64)
    const int sc = (tid & 3) << 3;      // element col 0,8,16,24
    const ushort* Ag = A  + (m0 + sr) * (long)lda + sc;
    const ushort* Bg = Bm + (n0 + sr) * (long)ldb + sc;
    ushort* lA = sA + tid * 8;          // *8 elements = 16 B
    ushort* lB = sB + tid * 8;

    for (int k0 = 0; k0 < K; k0 += 32) {
        __syncthreads();                 // previous tile fully consumed
        glds16(Ag + k0, lA);
        glds16(Ag + 64 * (long)lda + k0, lA + 2048);
        glds16(Bg + k0, lB);
        glds16(Bg + 64 * (long)ldb + k0, lB + 2048);
        __syncthreads();                 // DMA drained (vmcnt(0) at barrier)

        short8 af[4], bf[4];
        #pragma unroll
        for (int i = 0; i < 4; ++i)
            af[i] = *(const short8*)&sA[(wr * 64 + i * 16 + lrow) * 32 + lko];
        #pragma unroll
        for (int j = 0; j < 4; ++j)
            bf[j] = *(const short8*)&sB[(wc * 64 + j * 16 + lrow) * 32 + lko];

        #pragma unroll
        for (int i = 0; i < 4; ++i)
            #pragma unroll
            for (int j = 0; j < 4; ++j)
                acc[i][j] = __builtin_amdgcn_mfma_f32_16x16x32_bf16(
                    af[i], bf[j], acc[i][j], 0, 0, 0);
    }

    // C/D mapping: col = lane&15, row = (lane>>4)*4 + reg.
    const int r0 = (lane >> 4) * 4;
    const int c0 = lane & 15;
    #pragma unroll
    for (int i = 0; i < 4; ++i) {
        #pragma unroll
        for (int j = 0; j < 4; ++j) {
            long col = n0 + wc * 64 + j * 16 + c0;
            float bv = 0.f;
            if (EPI == 1) bv = bias[col];
            #pragma unroll
            for (int r = 0; r < 4; ++r) {
                long row = m0 + wr * 64 + i * 16 + r0 + r;
                float v = acc[i][j][r];
                if (EPI == 1) {
                    v += bv;
                    v = (v > 20.f) ? v : log1pf(__expf(v));  // softplus
                }
                long idx = row * (long)ldc + col;
                if (WF) Cf[idx] = v;
                if (WH) Ch[idx] = f2bf(v);
            }
        }
    }
}

// ---------------------------------------------------------------------------
// Sum NZ per-split partials; write f32 and optionally bf16.
// ---------------------------------------------------------------------------
template <int NZ, bool WH_>
__global__ __launch_bounds__(256) void reduce_k(
    const float4* __restrict__ parts, long stride4, int n4,
    float4* __restrict__ outF, us4* __restrict__ outH)
{
    int i = blockIdx.x * 256 + threadIdx.x;
    if (i >= n4) return;
    float4 s = parts[i];
    #pragma unroll
    for (int z = 1; z < NZ; ++z) {
        float4 v = parts[(long)z * stride4 + i];
        s.x += v.x; s.y += v.y; s.z += v.z; s.w += v.w;
    }
    if (outF) outF[i] = s;
    if (WH_) {
        us4 o; o.x = f2bf(s.x); o.y = f2bf(s.y); o.z = f2bf(s.z); o.w = f2bf(s.w);
        outH[i] = o;
    }
}

// ---------------------------------------------------------------------------
// Depthwise causal conv(4) + bias + SiLU.
// ---------------------------------------------------------------------------
__global__ __launch_bounds__(256) void conv_silu_kernel(
    const ushort* __restrict__ xz,
    const float* __restrict__ cw,
    const float* __restrict__ cb,
    ushort* __restrict__ xc)
{
    int gid = blockIdx.x * 256 + threadIdx.x;   // over 2048*4096
    int d  = gid & (DINNER - 1);
    int rl = gid >> 12;
    int l  = rl & (LL - 1);
    float acc = cb[d];
    #pragma unroll
    for (int j = 0; j < 4; ++j) {
        int li = l - 3 + j;
        if (li >= 0)
            acc += cw[d * 4 + j] * bf2f(xz[(long)(rl - 3 + j) * 8192 + d]);
    }
    float s = acc / (1.f + __expf(-acc));
    xc[gid] = f2bf(s);
}

// ---------------------------------------------------------------------------
// Chunked selective scan (3 phases).
// ---------------------------------------------------------------------------
__global__ __launch_bounds__(256) void scan_p1(
    const ushort* __restrict__ delta,
    const ushort* __restrict__ xc,
    const float*  __restrict__ xdbl,
    const float*  __restrict__ A_log,
    float* __restrict__ Hbuf,
    float* __restrict__ sumdt_buf)
{
    __shared__ float sB[CHUNK * 16];
    const int tid = threadIdx.x;
    const int k = blockIdx.y, b = blockIdx.z;
    const int d = blockIdx.x * 256 + tid;
    const int row0 = b * LL + k * CHUNK;

    #pragma unroll
    for (int i = 0; i < 4; ++i) {
        int idx = i * 256 + tid;                 // = t*16 + s
        sB[idx] = xdbl[(long)(row0 + (idx >> 4)) * XDBL_LD + DTRANK + (idx & 15)];
    }
    __syncthreads();

    float A[DSTATE];
    const float4* Ap = (const float4*)(A_log + d * DSTATE);
    #pragma unroll
    for (int i = 0; i < 4; ++i) {
        float4 v = Ap[i];
        A[i*4+0] = -__expf(v.x); A[i*4+1] = -__expf(v.y);
        A[i*4+2] = -__expf(v.z); A[i*4+3] = -__expf(v.w);
    }

    float H[DSTATE];
    #pragma unroll
    for (int s = 0; s < DSTATE; ++s) H[s] = 0.f;
    float sumdt = 0.f;

    for (int t = 0; t < CHUNK; ++t) {
        const long row = row0 + t;
        const float dt = bf2f(delta[row * DINNER + d]);
        const float xv = bf2f(xc[row * DINNER + d]);
        const float dx = dt * xv;
        sumdt += dt;
        #pragma unroll
        for (int s = 0; s < DSTATE; ++s) {
            float dA = __expf(dt * A[s]);
            H[s] = H[s] * dA + dx * sB[t * 16 + s];
        }
    }

    const long o = ((long)(b * NCH + k) * DINNER + d) * DSTATE;
    float4* Ho = (float4*)(Hbuf + o);
    #pragma unroll
    for (int i = 0; i < 4; ++i) {
        float4 v; v.x = H[i*4+0]; v.y = H[i*4+1]; v.z = H[i*4+2]; v.w = H[i*4+3];
        Ho[i] = v;
    }
    sumdt_buf[(b * NCH + k) * DINNER + d] = sumdt;
}

__global__ __launch_bounds__(256) void scan_p2(
    const float* __restrict__ A_log,
    const float* __restrict__ sumdt_buf,
    float* __restrict__ Hbuf)
{
    int gid = blockIdx.x * 256 + threadIdx.x;   // 131072 = 2*4096*16
    int b = gid >> 16;
    int rem = gid & 65535;
    int d = rem >> 4, s = rem & 15;
    float A = -__expf(A_log[d * DSTATE + s]);
    float h = 0.f;
    for (int k = 0; k < NCH; ++k) {
        long idx = ((long)(b * NCH + k) * DINNER + d) * DSTATE + s;
        float Hk = Hbuf[idx];
        float sd = sumdt_buf[(b * NCH + k) * DINNER + d];
        Hbuf[idx] = h;
        h = h * __expf(A * sd) + Hk;
    }
}

__global__ __launch_bounds__(256) void scan_p3(
    const ushort* __restrict__ delta,
    const ushort* __restrict__ xc,
    const float*  __restrict__ xdbl,
    const ushort* __restrict__ xz,
    const float*  __restrict__ A_log,
    const float*  __restrict__ Dp,
    const float*  __restrict__ hin,
    ushort* __restrict__ y)
{
    __shared__ float sBC[CHUNK * 32];
    const int tid = threadIdx.x;
    const int k = blockIdx.y, b = blockIdx.z;
    const int d = blockIdx.x * 256 + tid;
    const int row0 = b * LL + k * CHUNK;

    #pragma unroll
    for (int i = 0; i < 8; ++i) {
        int idx = i * 256 + tid;                 // = t*32 + c
        sBC[idx] = xdbl[(long)(row0 + (idx >> 5)) * XDBL_LD + DTRANK + (idx & 31)];
    }
    __syncthreads();

    float A[DSTATE];
    const float4* Ap = (const float4*)(A_log + d * DSTATE);
    #pragma unroll
    for (int i = 0; i < 4; ++i) {
        float4 v = Ap[i];
        A[i*4+0] = -__expf(v.x); A[i*4+1] = -__expf(v.y);
        A[i*4+2] = -__expf(v.z); A[i*4+3] = -__expf(v.w);
    }
    const float Dd = Dp[d];

    float h[DSTATE];
    const float4* Hp = (const float4*)(hin + ((long)(b * NCH + k) * DINNER + d) * DSTATE);
    #pragma unroll
    for (int i = 0; i < 4; ++i) {
        float4 v = Hp[i];
        h[i*4+0] = v.x; h[i*4+1] = v.y; h[i*4+2] = v.z; h[i*4+3] = v.w;
    }

    for (int t = 0; t < CHUNK; ++t) {
        const long row = row0 + t;
        const float dt = bf2f(delta[row * DINNER + d]);
        const float xv = bf2f(xc[row * DINNER + d]);
        const float dx = dt * xv;
        float yt = 0.f;
        #pragma unroll
        for (int s = 0; s < DSTATE; ++s) {
            float dA = __expf(dt * A[s]);
            h[s] = h[s] * dA + dx * sBC[t * 32 + s];
            yt += h[s] * sBC[t * 32 + 16 + s];
        }
        yt += xv * Dd;
        const float zv = bf2f(xz[row * 8192 + DINNER + d]);
        yt *= zv / (1.f + __expf(-zv));
        y[row * DINNER + d] = f2bf(yt);
    }
}

// ---------------------------------------------------------------------------
extern "C" void kernel_launch(void* const* d_in, const int* in_sizes, int n_in,
                              void* d_out, int out_size, void* d_ws, size_t ws_size,
                              hipStream_t stream)
{
    const float* hidden    = (const float*)d_in[0];
    const float* in_proj   = (const float*)d_in[1];
    const float* conv_w    = (const float*)d_in[2];
    const float* conv_b    = (const float*)d_in[3];
    const float* x_proj    = (const float*)d_in[4];
    const float* dt_proj_w = (const float*)d_in[5];
    const float* dt_proj_b = (const float*)d_in[6];
    const float* A_log     = (const float*)d_in[7];
    const float* Dp        = (const float*)d_in[8];
    const float* out_proj  = (const float*)d_in[9];
    float* out = (float*)d_out;

    // Workspace layout (bytes, all 16B aligned)
    char* ws = (char*)d_ws;
    ushort* xz_h    = (ushort*)(ws);                // 32 MiB
    ushort* xc      = (ushort*)(ws + 33554432);     // 16 MiB
    ushort* xpp     = (ushort*)(ws + 50331648);     // 2 MiB
    float*  xdbl    = (float*)(ws + 52428800);      // 2 MiB
    ushort* xdblh   = (ushort*)(ws + 54525952);     // 1 MiB
    ushort* delta_h = (ushort*)(ws + 55574528);     // 16 MiB
    ushort* yb      = (ushort*)(ws + 72351744);     // 16 MiB
    ushort* hid_h   = (ushort*)(ws + 89128960);     // 8 MiB
    // 32 MiB multi-use region at 97517568 (time-disjoint):
    //   (a) inp_h bf16 weights  (until gemm1)
    //   (b) xdbl split-K partials 16 x 2 MiB (gemm3 -> reduce)
    //   (c) Hbuf 8 MiB + sumdt 0.5 MiB (scan)
    //   (d) out_proj split-K partials 2 x 16 MiB (gemm6 -> reduce)
    ushort* inp_h   = (ushort*)(ws + 97517568);
    float*  parts   = (float*)(ws + 97517568);
    float*  Hbuf    = (float*)(ws + 97517568);
    float*  sumdt   = (float*)(ws + 105906176);
    ushort* dtp_h   = (ushort*)(ws + 131072000);    // 1 MiB
    ushort* outp_h  = (ushort*)(ws + 132120576);    // 16 MiB

    const int M = BB * LL;  // 2048

    // 0) f32 -> bf16 conversions
    cvt_kernel<<<(2048 * 2048) / 1024, 256, 0, stream>>>(
        (const float4*)hidden, (us4*)hid_h, (2048 * 2048) / 4);
    cvt_kernel<<<(8192 * 2048) / 1024, 256, 0, stream>>>(
        (const float4*)in_proj, (us4*)inp_h, (8192 * 2048) / 4);
    cvt_kernel<<<(4096 * 128) / 1024, 256, 0, stream>>>(
        (const float4*)dt_proj_w, (us4*)dtp_h, (4096 * 128) / 4);
    cvt_kernel<<<(2048 * 4096) / 1024, 256, 0, stream>>>(
        (const float4*)out_proj, (us4*)outp_h, (2048 * 4096) / 4);
    pad_xproj<<<(256 * 4096) / 256, 256, 0, stream>>>(x_proj, xpp);

    // 1) xz = hidden @ in_proj^T   (2048x8192 bf16)
    gemm_nt<0, false, true><<<dim3(8192 / 128, M / 128), 256, 0, stream>>>(
        hid_h, DMODEL, inp_h, DMODEL, nullptr, xz_h, 8192, DMODEL, nullptr);

    // 2) x_conv = silu(causal_conv(x) + conv_b)
    conv_silu_kernel<<<(M * DINNER) / 256, 256, 0, stream>>>(xz_h, conv_w, conv_b, xc);

    // 3) x_dbl = x_conv @ x_proj_pad^T, K split 16x256 -> partials -> reduce
    gemm_nt<0, true, false><<<dim3(XDBL_LD / 128, M / 128, 16), 256, 0, stream>>>(
        xc, DINNER, xpp, DINNER, parts, nullptr, XDBL_LD, DINNER / 16, nullptr);
    reduce_k<16, true><<<(M * XDBL_LD / 4 + 255) / 256, 256, 0, stream>>>(
        (const float4*)parts, (long)M * XDBL_LD / 4, M * XDBL_LD / 4,
        (float4*)xdbl, (us4*)xdblh);

    // 4) delta = softplus(dt_lo @ dt_proj_w^T + dt_proj_b)  (bf16)
    gemm_nt<1, false, true><<<dim3(DINNER / 128, M / 128), 256, 0, stream>>>(
        xdblh, XDBL_LD, dtp_h, DTRANK, nullptr, delta_h, DINNER, DTRANK, dt_proj_b);

    // 5) chunked selective scan + D-skip + silu(z) gating -> y (bf16)
    scan_p1<<<dim3(DINNER / 256, NCH, BB), 256, 0, stream>>>(
        delta_h, xc, xdbl, A_log, Hbuf, sumdt);
    scan_p2<<<(BB * DINNER * DSTATE) / 256, 256, 0, stream>>>(
        A_log, sumdt, Hbuf);
    scan_p3<<<dim3(DINNER / 256, NCH, BB), 256, 0, stream>>>(
        delta_h, xc, xdbl, xz_h, A_log, Dp, Hbuf, yb);

    // 6) out = y @ out_proj^T, K split 2x2048 -> partials -> reduce
    gemm_nt<0, true, false><<<dim3(DMODEL / 128, M / 128, 2), 256, 0, stream>>>(
        yb, DINNER, outp_h, DINNER, parts, nullptr, DMODEL, DINNER / 2, nullptr);
    reduce_k<2, false><<<(M * DMODEL / 4 + 255) / 256, 256, 0, stream>>>(
        (const float4*)parts, (long)M * DMODEL / 4, M * DMODEL / 4,
        (float4*)out, nullptr);
}

// Round 5
// 514.746 us; speedup vs baseline: 2.1332x; 1.0044x over previous
//
#include <hip/hip_runtime.h>
#include <hip/hip_bf16.h>
#include <stdint.h>

// Problem constants
#define BB 2
#define LL 1024
#define DMODEL 2048
#define DINNER 4096
#define DSTATE 16
#define DTRANK 128
#define XDBL_LD 256   // x_proj rows padded 160 -> 256
#define CHUNK 64
#define NCH (LL / CHUNK)   // 16

typedef unsigned short ushort;
using short8 = __attribute__((ext_vector_type(8))) short;
using f32x16 = __attribute__((ext_vector_type(16))) float;
using us4    = __attribute__((ext_vector_type(4))) ushort;

__device__ __forceinline__ float bf2f(ushort u) {
    union { uint32_t i; float f; } v; v.i = ((uint32_t)u) << 16; return v.f;
}
__device__ __forceinline__ ushort f2bf(float f) {
    union { float f; uint32_t i; } v; v.f = f;
    uint32_t lsb = (v.i >> 16) & 1u;
    uint32_t r = v.i + 0x7FFFu + lsb;   // RNE
    return (ushort)(r >> 16);
}

// Async global->LDS, 16B per lane (lane-ordered, unpadded LDS dest).
__device__ __forceinline__ void glds16(const ushort* g, ushort* l) {
    __builtin_amdgcn_global_load_lds(
        (const __attribute__((address_space(1))) void*)g,
        (__attribute__((address_space(3))) void*)l,
        16, 0, 0);
}

// ---------------------------------------------------------------------------
// Fused f32->bf16 conversion of all weights/activations + x_proj zero-pad.
// Segments (float4 units): hidden 1048576 | in_proj 4194304 | dt_proj 131072
// | out_proj 2097152 | xpp 262144 (first 163840 from x_proj, rest zeros).
// Total 7733248 float4 = 30208 blocks x 256.
// ---------------------------------------------------------------------------
__global__ __launch_bounds__(256) void cvt_all(
    const float4* __restrict__ hidden, const float4* __restrict__ inproj,
    const float4* __restrict__ dtw, const float4* __restrict__ outp,
    const float4* __restrict__ xproj,
    us4* __restrict__ hid_h, us4* __restrict__ inp_h, us4* __restrict__ dtp_h,
    us4* __restrict__ outp_h, us4* __restrict__ xpp)
{
    long i = (long)blockIdx.x * 256 + threadIdx.x;
    const float4* src; us4* dst; long j;
    if (i < 1048576)      { src = hidden; dst = hid_h;  j = i; }
    else if (i < 5242880) { src = inproj; dst = inp_h;  j = i - 1048576; }
    else if (i < 5373952) { src = dtw;    dst = dtp_h;  j = i - 5242880; }
    else if (i < 7471104) { src = outp;   dst = outp_h; j = i - 5373952; }
    else {
        j = i - 7471104; dst = xpp;
        if (j >= 163840) { us4 z = {0, 0, 0, 0}; dst[j] = z; return; }
        src = xproj;
    }
    float4 v = src[j];
    us4 o; o.x = f2bf(v.x); o.y = f2bf(v.y); o.z = f2bf(v.z); o.w = f2bf(v.w);
    dst[j] = o;
}

// ---------------------------------------------------------------------------
// NT GEMM: C[M,N] = A[M,K] bf16 row-major * B[N,K]^T bf16 row-major.
// 128x128 tile, 4 waves of 64x64 as 2x2 of 32x32x16 MFMA, global_load_lds
// staging. K-split via blockIdx.z (per-split partials). XCD-aware tile
// swizzle when gridDim.x % 8 == 0 (n-strip per XCD for L2 B-reuse).
// ---------------------------------------------------------------------------
template <int EPI, bool WF, bool WH>
__global__ __launch_bounds__(256) void gemm_nt(
    const ushort* __restrict__ A, int lda,
    const ushort* __restrict__ Bm, int ldb,
    float* __restrict__ Cf, ushort* __restrict__ Ch, int ldc,
    int K, const float* __restrict__ bias)
{
    __shared__ __align__(16) ushort sA[128 * 32];
    __shared__ __align__(16) ushort sB[128 * 32];

    const int tid  = threadIdx.x;
    const int lane = tid & 63;
    const int wave = tid >> 6;
    const int wr = wave >> 1, wc = wave & 1;

    // XCD-aware tile swizzle
    const int NT = gridDim.x, MT = gridDim.y;
    int mt, nt;
    if ((NT & 7) == 0) {
        int lin   = blockIdx.y * NT + blockIdx.x;
        int strip = NT >> 3;
        int xcd   = lin & 7;
        int idx   = lin >> 3;          // 0 .. strip*MT-1
        nt = xcd * strip + (idx % strip);
        mt = idx / strip;
    } else { mt = blockIdx.y; nt = blockIdx.x; }
    const long m0 = (long)mt * 128;
    const long n0 = (long)nt * 128;

    // K-split offsets
    const long zoff = (long)blockIdx.z;
    A  += zoff * (long)K;
    Bm += zoff * (long)K;
    const long Mrows = (long)MT * 128;
    if (WF) Cf += zoff * Mrows * (long)ldc;
    if (WH) Ch += zoff * Mrows * (long)ldc;

    f32x16 acc[2][2] = {};

    const int l31 = lane & 31;
    const int lhk = (lane >> 5) << 3;   // k sub-offset 0 or 8

    // staging geometry: thread t covers tile byte offset t*16 (and +4096)
    const int sr = tid >> 2;            // row 0..63 (second call adds 64)
    const int sc = (tid & 3) << 3;      // element col 0,8,16,24
    const ushort* Ag = A  + (m0 + sr) * (long)lda + sc;
    const ushort* Bg = Bm + (n0 + sr) * (long)ldb + sc;
    ushort* lA = sA + tid * 8;          // *8 elements = 16 B
    ushort* lB = sB + tid * 8;

    for (int k0 = 0; k0 < K; k0 += 32) {
        __syncthreads();                 // previous tile fully consumed
        glds16(Ag + k0, lA);
        glds16(Ag + 64 * (long)lda + k0, lA + 2048);
        glds16(Bg + k0, lB);
        glds16(Bg + 64 * (long)ldb + k0, lB + 2048);
        __syncthreads();                 // DMA drained

        short8 af[2][2], bfr[2][2];      // [m/n-half][k-step]
        #pragma unroll
        for (int i = 0; i < 2; ++i)
            #pragma unroll
            for (int ks = 0; ks < 2; ++ks) {
                af[i][ks]  = *(const short8*)&sA[(wr * 64 + i * 32 + l31) * 32 + ks * 16 + lhk];
                bfr[i][ks] = *(const short8*)&sB[(wc * 64 + i * 32 + l31) * 32 + ks * 16 + lhk];
            }

        #pragma unroll
        for (int ks = 0; ks < 2; ++ks)
            #pragma unroll
            for (int i = 0; i < 2; ++i)
                #pragma unroll
                for (int j = 0; j < 2; ++j)
                    acc[i][j] = __builtin_amdgcn_mfma_f32_32x32x16_bf16(
                        af[i][ks], bfr[j][ks], acc[i][j], 0, 0, 0);
    }

    // 32x32 C/D mapping (m74/m101): col = lane&31,
    // row = (reg&3) + 8*(reg>>2) + 4*(lane>>5).
    const int rq = (lane >> 5) << 2;
    #pragma unroll
    for (int i = 0; i < 2; ++i) {
        #pragma unroll
        for (int j = 0; j < 2; ++j) {
            long col = n0 + wc * 64 + j * 32 + l31;
            float bv = 0.f;
            if (EPI == 1) bv = bias[col];
            #pragma unroll
            for (int reg = 0; reg < 16; ++reg) {
                int rin = (reg & 3) + ((reg >> 2) << 3) + rq;
                long row = m0 + wr * 64 + i * 32 + rin;
                float v = acc[i][j][reg];
                if (EPI == 1) {
                    v += bv;
                    v = (v > 20.f) ? v : log1pf(__expf(v));  // softplus
                }
                long idx = row * (long)ldc + col;
                if (WF) Cf[idx] = v;
                if (WH) Ch[idx] = f2bf(v);
            }
        }
    }
}

// ---------------------------------------------------------------------------
// Sum NZ per-split partials; write f32 and optionally bf16.
// ---------------------------------------------------------------------------
template <int NZ, bool WH_>
__global__ __launch_bounds__(256) void reduce_k(
    const float4* __restrict__ parts, long stride4, int n4,
    float4* __restrict__ outF, us4* __restrict__ outH)
{
    int i = blockIdx.x * 256 + threadIdx.x;
    if (i >= n4) return;
    float4 s = parts[i];
    #pragma unroll
    for (int z = 1; z < NZ; ++z) {
        float4 v = parts[(long)z * stride4 + i];
        s.x += v.x; s.y += v.y; s.z += v.z; s.w += v.w;
    }
    if (outF) outF[i] = s;
    if (WH_) {
        us4 o; o.x = f2bf(s.x); o.y = f2bf(s.y); o.z = f2bf(s.z); o.w = f2bf(s.w);
        outH[i] = o;
    }
}

// ---------------------------------------------------------------------------
// Depthwise causal conv(4) + bias + SiLU.
// ---------------------------------------------------------------------------
__global__ __launch_bounds__(256) void conv_silu_kernel(
    const ushort* __restrict__ xz,
    const float* __restrict__ cw,
    const float* __restrict__ cb,
    ushort* __restrict__ xc)
{
    int gid = blockIdx.x * 256 + threadIdx.x;   // over 2048*4096
    int d  = gid & (DINNER - 1);
    int rl = gid >> 12;
    int l  = rl & (LL - 1);
    float acc = cb[d];
    #pragma unroll
    for (int j = 0; j < 4; ++j) {
        int li = l - 3 + j;
        if (li >= 0)
            acc += cw[d * 4 + j] * bf2f(xz[(long)(rl - 3 + j) * 8192 + d]);
    }
    float s = acc / (1.f + __expf(-acc));
    xc[gid] = f2bf(s);
}

// ---------------------------------------------------------------------------
// Chunked selective scan (3 phases).
// ---------------------------------------------------------------------------
__global__ __launch_bounds__(256) void scan_p1(
    const ushort* __restrict__ delta,
    const ushort* __restrict__ xc,
    const float*  __restrict__ xdbl,
    const float*  __restrict__ A_log,
    float* __restrict__ Hbuf,
    float* __restrict__ sumdt_buf)
{
    __shared__ float sB[CHUNK * 16];
    const int tid = threadIdx.x;
    const int k = blockIdx.y, b = blockIdx.z;
    const int d = blockIdx.x * 256 + tid;
    const int row0 = b * LL + k * CHUNK;

    #pragma unroll
    for (int i = 0; i < 4; ++i) {
        int idx = i * 256 + tid;                 // = t*16 + s
        sB[idx] = xdbl[(long)(row0 + (idx >> 4)) * XDBL_LD + DTRANK + (idx & 15)];
    }
    __syncthreads();

    float A[DSTATE];
    const float4* Ap = (const float4*)(A_log + d * DSTATE);
    #pragma unroll
    for (int i = 0; i < 4; ++i) {
        float4 v = Ap[i];
        A[i*4+0] = -__expf(v.x); A[i*4+1] = -__expf(v.y);
        A[i*4+2] = -__expf(v.z); A[i*4+3] = -__expf(v.w);
    }

    float H[DSTATE];
    #pragma unroll
    for (int s = 0; s < DSTATE; ++s) H[s] = 0.f;
    float sumdt = 0.f;

    for (int t = 0; t < CHUNK; ++t) {
        const long row = row0 + t;
        const float dt = bf2f(delta[row * DINNER + d]);
        const float xv = bf2f(xc[row * DINNER + d]);
        const float dx = dt * xv;
        sumdt += dt;
        #pragma unroll
        for (int s = 0; s < DSTATE; ++s) {
            float dA = __expf(dt * A[s]);
            H[s] = H[s] * dA + dx * sB[t * 16 + s];
        }
    }

    const long o = ((long)(b * NCH + k) * DINNER + d) * DSTATE;
    float4* Ho = (float4*)(Hbuf + o);
    #pragma unroll
    for (int i = 0; i < 4; ++i) {
        float4 v; v.x = H[i*4+0]; v.y = H[i*4+1]; v.z = H[i*4+2]; v.w = H[i*4+3];
        Ho[i] = v;
    }
    sumdt_buf[(b * NCH + k) * DINNER + d] = sumdt;
}

__global__ __launch_bounds__(256) void scan_p2(
    const float* __restrict__ A_log,
    const float* __restrict__ sumdt_buf,
    float* __restrict__ Hbuf)
{
    int gid = blockIdx.x * 256 + threadIdx.x;   // 131072 = 2*4096*16
    int b = gid >> 16;
    int rem = gid & 65535;
    int d = rem >> 4, s = rem & 15;
    float A = -__expf(A_log[d * DSTATE + s]);
    float h = 0.f;
    for (int k = 0; k < NCH; ++k) {
        long idx = ((long)(b * NCH + k) * DINNER + d) * DSTATE + s;
        float Hk = Hbuf[idx];
        float sd = sumdt_buf[(b * NCH + k) * DINNER + d];
        Hbuf[idx] = h;
        h = h * __expf(A * sd) + Hk;
    }
}

__global__ __launch_bounds__(256) void scan_p3(
    const ushort* __restrict__ delta,
    const ushort* __restrict__ xc,
    const float*  __restrict__ xdbl,
    const ushort* __restrict__ xz,
    const float*  __restrict__ A_log,
    const float*  __restrict__ Dp,
    const float*  __restrict__ hin,
    ushort* __restrict__ y)
{
    __shared__ float sBC[CHUNK * 32];
    const int tid = threadIdx.x;
    const int k = blockIdx.y, b = blockIdx.z;
    const int d = blockIdx.x * 256 + tid;
    const int row0 = b * LL + k * CHUNK;

    #pragma unroll
    for (int i = 0; i < 8; ++i) {
        int idx = i * 256 + tid;                 // = t*32 + c
        sBC[idx] = xdbl[(long)(row0 + (idx >> 5)) * XDBL_LD + DTRANK + (idx & 31)];
    }
    __syncthreads();

    float A[DSTATE];
    const float4* Ap = (const float4*)(A_log + d * DSTATE);
    #pragma unroll
    for (int i = 0; i < 4; ++i) {
        float4 v = Ap[i];
        A[i*4+0] = -__expf(v.x); A[i*4+1] = -__expf(v.y);
        A[i*4+2] = -__expf(v.z); A[i*4+3] = -__expf(v.w);
    }
    const float Dd = Dp[d];

    float h[DSTATE];
    const float4* Hp = (const float4*)(hin + ((long)(b * NCH + k) * DINNER + d) * DSTATE);
    #pragma unroll
    for (int i = 0; i < 4; ++i) {
        float4 v = Hp[i];
        h[i*4+0] = v.x; h[i*4+1] = v.y; h[i*4+2] = v.z; h[i*4+3] = v.w;
    }

    for (int t = 0; t < CHUNK; ++t) {
        const long row = row0 + t;
        const float dt = bf2f(delta[row * DINNER + d]);
        const float xv = bf2f(xc[row * DINNER + d]);
        const float dx = dt * xv;
        float yt = 0.f;
        #pragma unroll
        for (int s = 0; s < DSTATE; ++s) {
            float dA = __expf(dt * A[s]);
            h[s] = h[s] * dA + dx * sBC[t * 32 + s];
            yt += h[s] * sBC[t * 32 + 16 + s];
        }
        yt += xv * Dd;
        const float zv = bf2f(xz[row * 8192 + DINNER + d]);
        yt *= zv / (1.f + __expf(-zv));
        y[row * DINNER + d] = f2bf(yt);
    }
}

// ---------------------------------------------------------------------------
extern "C" void kernel_launch(void* const* d_in, const int* in_sizes, int n_in,
                              void* d_out, int out_size, void* d_ws, size_t ws_size,
                              hipStream_t stream)
{
    const float* hidden    = (const float*)d_in[0];
    const float* in_proj   = (const float*)d_in[1];
    const float* conv_w    = (const float*)d_in[2];
    const float* conv_b    = (const float*)d_in[3];
    const float* x_proj    = (const float*)d_in[4];
    const float* dt_proj_w = (const float*)d_in[5];
    const float* dt_proj_b = (const float*)d_in[6];
    const float* A_log     = (const float*)d_in[7];
    const float* Dp        = (const float*)d_in[8];
    const float* out_proj  = (const float*)d_in[9];
    float* out = (float*)d_out;

    // Workspace layout (bytes, all 16B aligned)
    char* ws = (char*)d_ws;
    ushort* xz_h    = (ushort*)(ws);                // 32 MiB
    ushort* xc      = (ushort*)(ws + 33554432);     // 16 MiB
    ushort* xpp     = (ushort*)(ws + 50331648);     // 2 MiB
    float*  xdbl    = (float*)(ws + 52428800);      // 2 MiB
    ushort* xdblh   = (ushort*)(ws + 54525952);     // 1 MiB
    ushort* delta_h = (ushort*)(ws + 55574528);     // 16 MiB
    ushort* yb      = (ushort*)(ws + 72351744);     // 16 MiB
    ushort* hid_h   = (ushort*)(ws + 89128960);     // 8 MiB
    // 32 MiB multi-use region at 97517568 (time-disjoint):
    //   (a) inp_h bf16 weights (until gemm1)
    //   (b) xdbl split-K partials (gemm3 -> reduce)
    //   (c) Hbuf 8 MiB + sumdt 0.5 MiB (scan)
    //   (d) out_proj split-K partials 2 x 16 MiB (gemm6 -> reduce)
    ushort* inp_h   = (ushort*)(ws + 97517568);
    float*  parts   = (float*)(ws + 97517568);
    float*  Hbuf    = (float*)(ws + 97517568);
    float*  sumdt   = (float*)(ws + 105906176);
    ushort* dtp_h   = (ushort*)(ws + 131072000);    // 1 MiB
    ushort* outp_h  = (ushort*)(ws + 132120576);    // 16 MiB

    const int M = BB * LL;  // 2048

    // 0) all f32 -> bf16 conversions + x_proj pad, one dispatch
    cvt_all<<<30208, 256, 0, stream>>>(
        (const float4*)hidden, (const float4*)in_proj, (const float4*)dt_proj_w,
        (const float4*)out_proj, (const float4*)x_proj,
        (us4*)hid_h, (us4*)inp_h, (us4*)dtp_h, (us4*)outp_h, (us4*)xpp);

    // 1) xz = hidden @ in_proj^T   (2048x8192 bf16)
    gemm_nt<0, false, true><<<dim3(8192 / 128, M / 128), 256, 0, stream>>>(
        hid_h, DMODEL, inp_h, DMODEL, nullptr, xz_h, 8192, DMODEL, nullptr);

    // 2) x_conv = silu(causal_conv(x) + conv_b)
    conv_silu_kernel<<<(M * DINNER) / 256, 256, 0, stream>>>(xz_h, conv_w, conv_b, xc);

    // 3) x_dbl = x_conv @ x_proj_pad^T, K split 16x256 -> partials -> reduce
    gemm_nt<0, true, false><<<dim3(XDBL_LD / 128, M / 128, 16), 256, 0, stream>>>(
        xc, DINNER, xpp, DINNER, parts, nullptr, XDBL_LD, DINNER / 16, nullptr);
    reduce_k<16, true><<<(M * XDBL_LD / 4 + 255) / 256, 256, 0, stream>>>(
        (const float4*)parts, (long)M * XDBL_LD / 4, M * XDBL_LD / 4,
        (float4*)xdbl, (us4*)xdblh);

    // 4) delta = softplus(dt_lo @ dt_proj_w^T + dt_proj_b)  (bf16)
    gemm_nt<1, false, true><<<dim3(DINNER / 128, M / 128), 256, 0, stream>>>(
        xdblh, XDBL_LD, dtp_h, DTRANK, nullptr, delta_h, DINNER, DTRANK, dt_proj_b);

    // 5) chunked selective scan + D-skip + silu(z) gating -> y (bf16)
    scan_p1<<<dim3(DINNER / 256, NCH, BB), 256, 0, stream>>>(
        delta_h, xc, xdbl, A_log, Hbuf, sumdt);
    scan_p2<<<(BB * DINNER * DSTATE) / 256, 256, 0, stream>>>(
        A_log, sumdt, Hbuf);
    scan_p3<<<dim3(DINNER / 256, NCH, BB), 256, 0, stream>>>(
        delta_h, xc, xdbl, xz_h, A_log, Dp, Hbuf, yb);

    // 6) out = y @ out_proj^T, K split 2x2048 -> partials -> reduce
    gemm_nt<0, true, false><<<dim3(DMODEL / 128, M / 128, 2), 256, 0, stream>>>(
        yb, DINNER, outp_h, DINNER, parts, nullptr, DMODEL, DINNER / 2, nullptr);
    reduce_k<2, false><<<(M * DMODEL / 4 + 255) / 256, 256, 0, stream>>>(
        (const float4*)parts, (long)M * DMODEL / 4, M * DMODEL / 4,
        (float4*)out, nullptr);
}

// Round 7
// 505.390 us; speedup vs baseline: 2.1727x; 1.0185x over previous
//
#include <hip/hip_runtime.h>
#include <hip/hip_bf16.h>
#include <stdint.h>

// Problem constants
#define BB 2
#define LL 1024
#define DMODEL 2048
#define DINNER 4096
#define DSTATE 16
#define DTRANK 128
#define XDBL_LD 256   // x_proj rows padded 160 -> 256
#define CHUNK 64
#define NCH (LL / CHUNK)   // 16

typedef unsigned short ushort;
using short8 = __attribute__((ext_vector_type(8))) short;
using f32x4  = __attribute__((ext_vector_type(4))) float;
using us4    = __attribute__((ext_vector_type(4))) ushort;

__device__ __forceinline__ float bf2f(ushort u) {
    union { uint32_t i; float f; } v; v.i = ((uint32_t)u) << 16; return v.f;
}
__device__ __forceinline__ ushort f2bf(float f) {
    union { float f; uint32_t i; } v; v.f = f;
    uint32_t lsb = (v.i >> 16) & 1u;
    uint32_t r = v.i + 0x7FFFu + lsb;   // RNE
    return (ushort)(r >> 16);
}

// Async global->LDS, 16B per lane (lane-ordered, unpadded LDS dest).
__device__ __forceinline__ void glds16(const ushort* g, ushort* l) {
    __builtin_amdgcn_global_load_lds(
        (const __attribute__((address_space(1))) void*)g,
        (__attribute__((address_space(3))) void*)l,
        16, 0, 0);
}

// ---------------------------------------------------------------------------
// Fused f32->bf16 conversion of all weights/activations + x_proj zero-pad.
// Segments (float4 units): hidden 1048576 | in_proj 4194304 | dt_proj 131072
// | out_proj 2097152 | xpp 262144 (first 163840 from x_proj, rest zeros).
// ---------------------------------------------------------------------------
__global__ __launch_bounds__(256) void cvt_all(
    const float4* __restrict__ hidden, const float4* __restrict__ inproj,
    const float4* __restrict__ dtw, const float4* __restrict__ outp,
    const float4* __restrict__ xproj,
    us4* __restrict__ hid_h, us4* __restrict__ inp_h, us4* __restrict__ dtp_h,
    us4* __restrict__ outp_h, us4* __restrict__ xpp)
{
    long i = (long)blockIdx.x * 256 + threadIdx.x;
    const float4* src; us4* dst; long j;
    if (i < 1048576)      { src = hidden; dst = hid_h;  j = i; }
    else if (i < 5242880) { src = inproj; dst = inp_h;  j = i - 1048576; }
    else if (i < 5373952) { src = dtw;    dst = dtp_h;  j = i - 5242880; }
    else if (i < 7471104) { src = outp;   dst = outp_h; j = i - 5373952; }
    else {
        j = i - 7471104; dst = xpp;
        if (j >= 163840) { us4 z = {0, 0, 0, 0}; dst[j] = z; return; }
        src = xproj;
    }
    float4 v = src[j];
    us4 o; o.x = f2bf(v.x); o.y = f2bf(v.y); o.z = f2bf(v.z); o.w = f2bf(v.w);
    dst[j] = o;
}

// ---------------------------------------------------------------------------
// NT GEMM: C[M,N] = A[M,K] bf16 row-major * B[N,K]^T bf16 row-major.
// 128x128 tile, 4 waves of 64x64, 16x16x32 bf16 MFMA, BK=64 (two 32-K
// substeps per barrier pair). global_load_lds staging, K-split via
// blockIdx.z, XCD swizzle. Requires K % 64 == 0.
// LDS layout: row-major 128 x 64; 32-row group c sits at +c*2048 elements.
// ---------------------------------------------------------------------------
template <int EPI, bool WF, bool WH>
__global__ __launch_bounds__(256) void gemm_nt(
    const ushort* __restrict__ A, int lda,
    const ushort* __restrict__ Bm, int ldb,
    float* __restrict__ Cf, ushort* __restrict__ Ch, int ldc,
    int K, const float* __restrict__ bias)
{
    __shared__ __align__(16) ushort sA[128 * 64];   // 16 KB
    __shared__ __align__(16) ushort sB[128 * 64];   // 16 KB

    const int tid  = threadIdx.x;
    const int lane = tid & 63;
    const int wave = tid >> 6;
    const int wr = wave >> 1, wc = wave & 1;

    // XCD-aware tile swizzle (n-strip per XCD for B L2 reuse)
    const int NT = gridDim.x, MT = gridDim.y;
    int mt, nt;
    if ((NT & 7) == 0) {
        int lin   = blockIdx.y * NT + blockIdx.x;
        int strip = NT >> 3;
        int xcd   = lin & 7;
        int idx   = lin >> 3;
        nt = xcd * strip + (idx % strip);
        mt = idx / strip;
    } else { mt = blockIdx.y; nt = blockIdx.x; }
    const long m0 = (long)mt * 128;
    const long n0 = (long)nt * 128;

    // K-split offsets
    const long zoff = (long)blockIdx.z;
    A  += zoff * (long)K;
    Bm += zoff * (long)K;
    const long Mrows = (long)MT * 128;
    if (WF) Cf += zoff * Mrows * (long)ldc;
    if (WH) Ch += zoff * Mrows * (long)ldc;

    f32x4 acc[4][4] = {};

    const int lrow = lane & 15;
    const int lko  = (lane >> 4) << 3;

    // staging: 128 rows x 64 cols bf16 = 128 B/row, 8 threads/row.
    // thread t stages element offset tid*8 = (t>>3)*64 + (t&7)*8, i.e.
    // row t>>3, cols (t&7)*8..+8; group c (rows +32c) at +c*2048 elements.
    const int sr = tid >> 3;            // 0..31
    const int sc = (tid & 7) << 3;      // element col 0..56
    const ushort* Ag = A  + (m0 + sr) * (long)lda + sc;
    const ushort* Bg = Bm + (n0 + sr) * (long)ldb + sc;
    ushort* lA = sA + tid * 8;
    ushort* lB = sB + tid * 8;

    for (int k0 = 0; k0 < K; k0 += 64) {
        __syncthreads();                 // previous tile fully consumed
        #pragma unroll
        for (int c = 0; c < 4; ++c) {
            glds16(Ag + (c * 32) * (long)lda + k0, lA + c * 2048);
            glds16(Bg + (c * 32) * (long)ldb + k0, lB + c * 2048);
        }
        __syncthreads();                 // DMA drained

        #pragma unroll
        for (int ks = 0; ks < 2; ++ks) {
            short8 af[4], bf[4];
            #pragma unroll
            for (int i = 0; i < 4; ++i)
                af[i] = *(const short8*)&sA[(wr * 64 + i * 16 + lrow) * 64 + ks * 32 + lko];
            #pragma unroll
            for (int j = 0; j < 4; ++j)
                bf[j] = *(const short8*)&sB[(wc * 64 + j * 16 + lrow) * 64 + ks * 32 + lko];

            #pragma unroll
            for (int i = 0; i < 4; ++i)
                #pragma unroll
                for (int j = 0; j < 4; ++j)
                    acc[i][j] = __builtin_amdgcn_mfma_f32_16x16x32_bf16(
                        af[i], bf[j], acc[i][j], 0, 0, 0);
        }
    }

    // C/D mapping: col = lane&15, row = (lane>>4)*4 + reg.
    const int r0 = (lane >> 4) * 4;
    const int c0 = lane & 15;
    #pragma unroll
    for (int i = 0; i < 4; ++i) {
        #pragma unroll
        for (int j = 0; j < 4; ++j) {
            long col = n0 + wc * 64 + j * 16 + c0;
            float bv = 0.f;
            if (EPI == 1) bv = bias[col];
            #pragma unroll
            for (int r = 0; r < 4; ++r) {
                long row = m0 + wr * 64 + i * 16 + r0 + r;
                float v = acc[i][j][r];
                if (EPI == 1) {
                    v += bv;
                    v = (v > 20.f) ? v : log1pf(__expf(v));  // softplus
                }
                long idx = row * (long)ldc + col;
                if (WF) Cf[idx] = v;
                if (WH) Ch[idx] = f2bf(v);
            }
        }
    }
}

// ---------------------------------------------------------------------------
// Sum NZ per-split partials; write f32 and optionally bf16.
// ---------------------------------------------------------------------------
template <int NZ, bool WH_>
__global__ __launch_bounds__(256) void reduce_k(
    const float4* __restrict__ parts, long stride4, int n4,
    float4* __restrict__ outF, us4* __restrict__ outH)
{
    int i = blockIdx.x * 256 + threadIdx.x;
    if (i >= n4) return;
    float4 s = parts[i];
    #pragma unroll
    for (int z = 1; z < NZ; ++z) {
        float4 v = parts[(long)z * stride4 + i];
        s.x += v.x; s.y += v.y; s.z += v.z; s.w += v.w;
    }
    if (outF) outF[i] = s;
    if (WH_) {
        us4 o; o.x = f2bf(s.x); o.y = f2bf(s.y); o.z = f2bf(s.z); o.w = f2bf(s.w);
        outH[i] = o;
    }
}

// ---------------------------------------------------------------------------
// Depthwise causal conv(4) + bias + SiLU.
// ---------------------------------------------------------------------------
__global__ __launch_bounds__(256) void conv_silu_kernel(
    const ushort* __restrict__ xz,
    const float* __restrict__ cw,
    const float* __restrict__ cb,
    ushort* __restrict__ xc)
{
    int gid = blockIdx.x * 256 + threadIdx.x;   // over 2048*4096
    int d  = gid & (DINNER - 1);
    int rl = gid >> 12;
    int l  = rl & (LL - 1);
    float acc = cb[d];
    #pragma unroll
    for (int j = 0; j < 4; ++j) {
        int li = l - 3 + j;
        if (li >= 0)
            acc += cw[d * 4 + j] * bf2f(xz[(long)(rl - 3 + j) * 8192 + d]);
    }
    float s = acc / (1.f + __expf(-acc));
    xc[gid] = f2bf(s);
}

// ---------------------------------------------------------------------------
// Chunked selective scan (3 phases).
// ---------------------------------------------------------------------------
__global__ __launch_bounds__(256) void scan_p1(
    const ushort* __restrict__ delta,
    const ushort* __restrict__ xc,
    const float*  __restrict__ xdbl,
    const float*  __restrict__ A_log,
    float* __restrict__ Hbuf,
    float* __restrict__ sumdt_buf)
{
    __shared__ float sB[CHUNK * 16];
    const int tid = threadIdx.x;
    const int k = blockIdx.y, b = blockIdx.z;
    const int d = blockIdx.x * 256 + tid;
    const int row0 = b * LL + k * CHUNK;

    #pragma unroll
    for (int i = 0; i < 4; ++i) {
        int idx = i * 256 + tid;                 // = t*16 + s
        sB[idx] = xdbl[(long)(row0 + (idx >> 4)) * XDBL_LD + DTRANK + (idx & 15)];
    }
    __syncthreads();

    float A[DSTATE];
    const float4* Ap = (const float4*)(A_log + d * DSTATE);
    #pragma unroll
    for (int i = 0; i < 4; ++i) {
        float4 v = Ap[i];
        A[i*4+0] = -__expf(v.x); A[i*4+1] = -__expf(v.y);
        A[i*4+2] = -__expf(v.z); A[i*4+3] = -__expf(v.w);
    }

    float H[DSTATE];
    #pragma unroll
    for (int s = 0; s < DSTATE; ++s) H[s] = 0.f;
    float sumdt = 0.f;

    for (int t = 0; t < CHUNK; ++t) {
        const long row = row0 + t;
        const float dt = bf2f(delta[row * DINNER + d]);
        const float xv = bf2f(xc[row * DINNER + d]);
        const float dx = dt * xv;
        sumdt += dt;
        #pragma unroll
        for (int s = 0; s < DSTATE; ++s) {
            float dA = __expf(dt * A[s]);
            H[s] = H[s] * dA + dx * sB[t * 16 + s];
        }
    }

    const long o = ((long)(b * NCH + k) * DINNER + d) * DSTATE;
    float4* Ho = (float4*)(Hbuf + o);
    #pragma unroll
    for (int i = 0; i < 4; ++i) {
        float4 v; v.x = H[i*4+0]; v.y = H[i*4+1]; v.z = H[i*4+2]; v.w = H[i*4+3];
        Ho[i] = v;
    }
    sumdt_buf[(b * NCH + k) * DINNER + d] = sumdt;
}

__global__ __launch_bounds__(256) void scan_p2(
    const float* __restrict__ A_log,
    const float* __restrict__ sumdt_buf,
    float* __restrict__ Hbuf)
{
    int gid = blockIdx.x * 256 + threadIdx.x;   // 131072 = 2*4096*16
    int b = gid >> 16;
    int rem = gid & 65535;
    int d = rem >> 4, s = rem & 15;
    float A = -__expf(A_log[d * DSTATE + s]);
    float h = 0.f;
    for (int k = 0; k < NCH; ++k) {
        long idx = ((long)(b * NCH + k) * DINNER + d) * DSTATE + s;
        float Hk = Hbuf[idx];
        float sd = sumdt_buf[(b * NCH + k) * DINNER + d];
        Hbuf[idx] = h;
        h = h * __expf(A * sd) + Hk;
    }
}

__global__ __launch_bounds__(256) void scan_p3(
    const ushort* __restrict__ delta,
    const ushort* __restrict__ xc,
    const float*  __restrict__ xdbl,
    const ushort* __restrict__ xz,
    const float*  __restrict__ A_log,
    const float*  __restrict__ Dp,
    const float*  __restrict__ hin,
    ushort* __restrict__ y)
{
    __shared__ float sBC[CHUNK * 32];
    const int tid = threadIdx.x;
    const int k = blockIdx.y, b = blockIdx.z;
    const int d = blockIdx.x * 256 + tid;
    const int row0 = b * LL + k * CHUNK;

    #pragma unroll
    for (int i = 0; i < 8; ++i) {
        int idx = i * 256 + tid;                 // = t*32 + c
        sBC[idx] = xdbl[(long)(row0 + (idx >> 5)) * XDBL_LD + DTRANK + (idx & 31)];
    }
    __syncthreads();

    float A[DSTATE];
    const float4* Ap = (const float4*)(A_log + d * DSTATE);
    #pragma unroll
    for (int i = 0; i < 4; ++i) {
        float4 v = Ap[i];
        A[i*4+0] = -__expf(v.x); A[i*4+1] = -__expf(v.y);
        A[i*4+2] = -__expf(v.z); A[i*4+3] = -__expf(v.w);
    }
    const float Dd = Dp[d];

    float h[DSTATE];
    const float4* Hp = (const float4*)(hin + ((long)(b * NCH + k) * DINNER + d) * DSTATE);
    #pragma unroll
    for (int i = 0; i < 4; ++i) {
        float4 v = Hp[i];
        h[i*4+0] = v.x; h[i*4+1] = v.y; h[i*4+2] = v.z; h[i*4+3] = v.w;
    }

    for (int t = 0; t < CHUNK; ++t) {
        const long row = row0 + t;
        const float dt = bf2f(delta[row * DINNER + d]);
        const float xv = bf2f(xc[row * DINNER + d]);
        const float dx = dt * xv;
        float yt = 0.f;
        #pragma unroll
        for (int s = 0; s < DSTATE; ++s) {
            float dA = __expf(dt * A[s]);
            h[s] = h[s] * dA + dx * sBC[t * 32 + s];
            yt += h[s] * sBC[t * 32 + 16 + s];
        }
        yt += xv * Dd;
        const float zv = bf2f(xz[row * 8192 + DINNER + d]);
        yt *= zv / (1.f + __expf(-zv));
        y[row * DINNER + d] = f2bf(yt);
    }
}

// ---------------------------------------------------------------------------
extern "C" void kernel_launch(void* const* d_in, const int* in_sizes, int n_in,
                              void* d_out, int out_size, void* d_ws, size_t ws_size,
                              hipStream_t stream)
{
    const float* hidden    = (const float*)d_in[0];
    const float* in_proj   = (const float*)d_in[1];
    const float* conv_w    = (const float*)d_in[2];
    const float* conv_b    = (const float*)d_in[3];
    const float* x_proj    = (const float*)d_in[4];
    const float* dt_proj_w = (const float*)d_in[5];
    const float* dt_proj_b = (const float*)d_in[6];
    const float* A_log     = (const float*)d_in[7];
    const float* Dp        = (const float*)d_in[8];
    const float* out_proj  = (const float*)d_in[9];
    float* out = (float*)d_out;

    // Workspace layout (bytes, all 16B aligned)
    char* ws = (char*)d_ws;
    ushort* xz_h    = (ushort*)(ws);                // 32 MiB  (dead after scan_p3)
    ushort* xc      = (ushort*)(ws + 33554432);     // 16 MiB  (dead after scan_p3)
    ushort* xpp     = (ushort*)(ws + 50331648);     // 2 MiB
    float*  xdbl    = (float*)(ws + 52428800);      // 2 MiB   (dead after scan_p3)
    ushort* xdblh   = (ushort*)(ws + 54525952);     // 1 MiB
    ushort* delta_h = (ushort*)(ws + 55574528);     // 16 MiB  (dead after scan_p3)
    ushort* yb      = (ushort*)(ws + 72351744);     // 16 MiB
    ushort* hid_h   = (ushort*)(ws + 89128960);     // 8 MiB
    // 32 MiB multi-use region at 97517568 (time-disjoint):
    //   (a) inp_h bf16 weights (until gemm1)
    //   (b) xdbl split-K partials 16 x 2 MiB (gemm3 -> reduce)
    //   (c) Hbuf 8 MiB + sumdt 0.5 MiB (scan)
    ushort* inp_h   = (ushort*)(ws + 97517568);
    float*  parts   = (float*)(ws + 97517568);
    float*  Hbuf    = (float*)(ws + 97517568);
    float*  sumdt   = (float*)(ws + 105906176);
    ushort* dtp_h   = (ushort*)(ws + 131072000);    // 1 MiB
    ushort* outp_h  = (ushort*)(ws + 132120576);    // 16 MiB
    // out_proj split-4 partials: 4 x 16 MiB = 64 MiB aliasing ws[0..64 MiB)
    // (xz_h, xc, xpp, xdbl, xdblh, first part of delta_h — dead after scan_p3;
    //  yb at 72351744 is NOT overlapped: 4*16 MiB = 67108864 < 72351744)
    float*  parts2  = (float*)(ws);

    const int M = BB * LL;  // 2048

    // 0) all f32 -> bf16 conversions + x_proj pad, one dispatch
    cvt_all<<<30208, 256, 0, stream>>>(
        (const float4*)hidden, (const float4*)in_proj, (const float4*)dt_proj_w,
        (const float4*)out_proj, (const float4*)x_proj,
        (us4*)hid_h, (us4*)inp_h, (us4*)dtp_h, (us4*)outp_h, (us4*)xpp);

    // 1) xz = hidden @ in_proj^T   (2048x8192 bf16)
    gemm_nt<0, false, true><<<dim3(8192 / 128, M / 128), 256, 0, stream>>>(
        hid_h, DMODEL, inp_h, DMODEL, nullptr, xz_h, 8192, DMODEL, nullptr);

    // 2) x_conv = silu(causal_conv(x) + conv_b)
    conv_silu_kernel<<<(M * DINNER) / 256, 256, 0, stream>>>(xz_h, conv_w, conv_b, xc);

    // 3) x_dbl = x_conv @ x_proj_pad^T, K split 16x256 -> partials -> reduce
    gemm_nt<0, true, false><<<dim3(XDBL_LD / 128, M / 128, 16), 256, 0, stream>>>(
        xc, DINNER, xpp, DINNER, parts, nullptr, XDBL_LD, DINNER / 16, nullptr);
    reduce_k<16, true><<<(M * XDBL_LD / 4 + 255) / 256, 256, 0, stream>>>(
        (const float4*)parts, (long)M * XDBL_LD / 4, M * XDBL_LD / 4,
        (float4*)xdbl, (us4*)xdblh);

    // 4) delta = softplus(dt_lo @ dt_proj_w^T + dt_proj_b)  (bf16)
    gemm_nt<1, false, true><<<dim3(DINNER / 128, M / 128), 256, 0, stream>>>(
        xdblh, XDBL_LD, dtp_h, DTRANK, nullptr, delta_h, DINNER, DTRANK, dt_proj_b);

    // 5) chunked selective scan + D-skip + silu(z) gating -> y (bf16)
    scan_p1<<<dim3(DINNER / 256, NCH, BB), 256, 0, stream>>>(
        delta_h, xc, xdbl, A_log, Hbuf, sumdt);
    scan_p2<<<(BB * DINNER * DSTATE) / 256, 256, 0, stream>>>(
        A_log, sumdt, Hbuf);
    scan_p3<<<dim3(DINNER / 256, NCH, BB), 256, 0, stream>>>(
        delta_h, xc, xdbl, xz_h, A_log, Dp, Hbuf, yb);

    // 6) out = y @ out_proj^T, K split 4x1024 -> partials -> reduce
    gemm_nt<0, true, false><<<dim3(DMODEL / 128, M / 128, 4), 256, 0, stream>>>(
        yb, DINNER, outp_h, DINNER, parts2, nullptr, DMODEL, DINNER / 4, nullptr);
    reduce_k<4, false><<<(M * DMODEL / 4 + 255) / 256, 256, 0, stream>>>(
        (const float4*)parts2, (long)M * DMODEL / 4, M * DMODEL / 4,
        (float4*)out, nullptr);
}